// Round 8
// baseline (280.725 us; speedup 1.0000x reference)
//
#include <hip/hip_runtime.h>
#include <math.h>

// Single-query MHA, algebraically collapsed:
//   s[l,h] = x_l . p_h         (p_h = Wk_h^T q_h / sqrt(D); k-bias shift cancels in softmax)
//   z_h    = sum_l softmax(s)_lh * x_l
//   attn   = Wv z + bv ; out = Wo attn + bo
// All fp32. No max-subtraction needed: |s| ~ N(0,1), max ~ 5 << 88 (fp32 exp range).
//
// v8 (attn_wave): SINGLE pass over x, ZERO barriers, ZERO hot-loop LDS.
// Wave (g,j) is fully autonomous: heads {2j,2j+1}, rows == g (mod 2).
// Per row: load row into regs (4x float4, coalesced), dot vs 2 register-held
// p-slices, 2-value transpose-butterfly (7 shfl) + 1 exp, accumulate w*x into
// 32 acc regs from the SAME registers (no re-read). The 4 waves per group read
// identical addresses -> L1 broadcast (HBM stays 1x134MB). Each wave writes a
// disjoint partial slice (2 per block). ~105 VGPRs -> (512,2) cap 128, no
// spill (R1/R4 lesson), 2 blocks/CU.
// Evidence: every barrier-free+spill-free+2blk/CU stream ran ~28us (R4 accum);
// every barrier-per-tile fused kernel ~70us; two-pass pays x twice.

#define L_SEQ   32768
#define E_DIM   1024
#define NHEAD   8
#define HDIM    128

// ---------------- q = Wq x0 + bq : wave-per-output GEMV ----------------
__global__ __launch_bounds__(256) void proj_q(
    const float* __restrict__ W, const float* __restrict__ bias,
    const float* __restrict__ x, float* __restrict__ q)
{
  const int t = threadIdx.x, wave = t >> 6, lane = t & 63;
  const int o = blockIdx.x * 4 + wave;
  const float4* Wr = (const float4*)(W + (size_t)o * E_DIM);
  const float4* xr = (const float4*)x;   // row 0 of x
  float a = 0.f;
#pragma unroll
  for (int k = 0; k < 4; ++k) {
    float4 wv = Wr[lane + 64 * k];
    float4 xv = xr[lane + 64 * k];
    a += wv.x * xv.x + wv.y * xv.y + wv.z * xv.z + wv.w * xv.w;
  }
#pragma unroll
  for (int m = 1; m < 64; m <<= 1) a += __shfl_xor(a, m, 64);
  if (lane == 0) q[o] = a + bias[o];
}

// ---------------- P_T[h][e] = (1/sqrt(D)) sum_d q[h*128+d] * Wk[h*128+d][e] ----------------
__global__ __launch_bounds__(128) void make_p(
    const float* __restrict__ W, const float* __restrict__ q,
    float* __restrict__ P_T)
{
  const int h = blockIdx.y;
  const int e = blockIdx.x * 128 + threadIdx.x;
  const float* qh = q + h * HDIM;                              // lane-uniform (scalarized)
  const float* Wb = W + ((size_t)E_DIM + (size_t)h * HDIM) * E_DIM + e;  // Wk block rows
  float a[8];
#pragma unroll
  for (int j = 0; j < 8; ++j) a[j] = 0.f;
#pragma unroll 2
  for (int d = 0; d < HDIM; d += 8) {
#pragma unroll
    for (int j = 0; j < 8; ++j)
      a[j] += qh[d + j] * Wb[(size_t)(d + j) * E_DIM];
  }
  const float s = ((a[0] + a[1]) + (a[2] + a[3])) + ((a[4] + a[5]) + (a[6] + a[7]));
  P_T[h * E_DIM + e] = s * 0.08838834764831845f;               // 1/sqrt(128)
}

// ---------------- single-pass wave-autonomous attention core ----------------
// Block: rows [row0, row0+rows_per_blk). Wave w = (g = w>>2, j = w&3):
// rows row0+g, row0+g+2, ... (rows_per_blk/2 rows); heads {2j, 2j+1}.
// Writes partial_z[2*blk+g][2j..2j+1][:] and partial_sumw[2*blk+g][2j..2j+1].
__global__ __launch_bounds__(512, 2) void attn_wave(
    const float* __restrict__ x,
    const float* __restrict__ P_T,       // [8][1024]
    float* __restrict__ partial_z,       // [2*nblk][8][1024]
    float* __restrict__ partial_sumw,    // [2*nblk][8]
    int rows_per_blk)
{
  const int t = threadIdx.x;
  const int wave = t >> 6;
  const int lane = t & 63;
  const int g = wave >> 2;          // row parity group
  const int j = wave & 3;           // head pair {2j, 2j+1}
  const size_t row0 = (size_t)blockIdx.x * rows_per_blk;
  const int iters = rows_per_blk >> 1;

  // p slices for this wave's two heads: cols 4*lane + 256k + {0..3}
  float4 p0[4], p1[4];
  {
    const float4* pr0 = (const float4*)(P_T + (size_t)(2 * j) * E_DIM) + lane;
    const float4* pr1 = (const float4*)(P_T + (size_t)(2 * j + 1) * E_DIM) + lane;
#pragma unroll
    for (int k = 0; k < 4; ++k) { p0[k] = pr0[64 * k]; p1[k] = pr1[64 * k]; }
  }

  float4 acc0[4], acc1[4];    // heads 2j, 2j+1; cols 4*lane + 256k
#pragma unroll
  for (int k = 0; k < 4; ++k) {
    acc0[k] = make_float4(0.f, 0.f, 0.f, 0.f);
    acc1[k] = make_float4(0.f, 0.f, 0.f, 0.f);
  }
  float sumw_own = 0.f;       // head (2j + lane&1), replicated within parity

  const int par = lane & 1;

  // base pointer: row (row0 + g), advancing 2 rows (2048 floats) per iter
  const float4* xb = (const float4*)(x + (row0 + g) * E_DIM) + lane;

  float4 xv[4];
#pragma unroll
  for (int k = 0; k < 4; ++k) xv[k] = xb[64 * k];

  for (int i = 0; i < iters; ++i) {
    float4 xn[4];
    if (i + 1 < iters) {
      const float4* xnp = xb + (size_t)(i + 1) * 512;   // +2048 floats
#pragma unroll
      for (int k = 0; k < 4; ++k) xn[k] = xnp[64 * k];
    }

    // two head-dots
    float v0 = 0.f, v1 = 0.f;
#pragma unroll
    for (int k = 0; k < 4; ++k) {
      v0 += xv[k].x * p0[k].x + xv[k].y * p0[k].y + xv[k].z * p0[k].z + xv[k].w * p0[k].w;
      v1 += xv[k].x * p1[k].x + xv[k].y * p1[k].y + xv[k].z * p1[k].z + xv[k].w * p1[k].w;
    }
    // 2-value transpose-butterfly: 1 splitting level, then 5 plain levels.
    // After: every lane holds the full dot for head (2j + lane&1).
    {
      float keep = par ? v1 : v0;
      float oth  = par ? v0 : v1;
      float s = keep + __shfl_xor(oth, 1, 64);
      s += __shfl_xor(s, 2, 64);
      s += __shfl_xor(s, 4, 64);
      s += __shfl_xor(s, 8, 64);
      s += __shfl_xor(s, 16, 64);
      s += __shfl_xor(s, 32, 64);
      const float w_own = __expf(s);
      sumw_own += w_own;
      const float w_oth = __shfl_xor(w_own, 1, 64);
      const float wA = par ? w_oth : w_own;   // head 2j
      const float wB = par ? w_own : w_oth;   // head 2j+1
#pragma unroll
      for (int k = 0; k < 4; ++k) {
        acc0[k].x += wA * xv[k].x;  acc0[k].y += wA * xv[k].y;
        acc0[k].z += wA * xv[k].z;  acc0[k].w += wA * xv[k].w;
        acc1[k].x += wB * xv[k].x;  acc1[k].y += wB * xv[k].y;
        acc1[k].z += wB * xv[k].z;  acc1[k].w += wB * xv[k].w;
      }
    }

    if (i + 1 < iters) {
#pragma unroll
      for (int k = 0; k < 4; ++k) xv[k] = xn[k];
    }
  }

  // write this wave's disjoint partial slice (vblk = 2*blk + g)
  const size_t vblk = 2 * (size_t)blockIdx.x + g;
  {
    float4* zd0 = (float4*)(partial_z + vblk * (NHEAD * E_DIM) + (size_t)(2 * j) * E_DIM) + lane;
    float4* zd1 = (float4*)(partial_z + vblk * (NHEAD * E_DIM) + (size_t)(2 * j + 1) * E_DIM) + lane;
#pragma unroll
    for (int k = 0; k < 4; ++k) { zd0[64 * k] = acc0[k]; zd1[64 * k] = acc1[k]; }
  }
  // sumw: all even lanes identical (head 2j), all odd identical (head 2j+1)
  if (lane < 2) partial_sumw[vblk * NHEAD + 2 * j + lane] = sumw_own;
}

// ---------------- reduce partials: zn[h][e] = sum_b pz / sum_b psumw ----------------
__global__ __launch_bounds__(256) void reduce_z(
    const float* __restrict__ partial_z,
    const float* __restrict__ partial_sumw,
    float* __restrict__ zn, int nvblk)
{
  __shared__ float red[256];
  __shared__ __align__(16) float swst[4][NHEAD];
  __shared__ float sumw_s[NHEAD];
  const int t = threadIdx.x;
  const int lane = t & 63, wave = t >> 6;

  float sw[NHEAD];
#pragma unroll
  for (int h = 0; h < NHEAD; ++h) sw[h] = 0.f;
  for (int b = t; b < nvblk; b += 256) {
    const float4* p = (const float4*)(partial_sumw + (size_t)b * NHEAD);
    float4 a0 = p[0], a1 = p[1];
    sw[0] += a0.x; sw[1] += a0.y; sw[2] += a0.z; sw[3] += a0.w;
    sw[4] += a1.x; sw[5] += a1.y; sw[6] += a1.z; sw[7] += a1.w;
  }
#pragma unroll
  for (int m = 1; m < 64; m <<= 1) {
#pragma unroll
    for (int h = 0; h < NHEAD; ++h) sw[h] += __shfl_xor(sw[h], m, 64);
  }
  if (lane == 0) {
#pragma unroll
    for (int h = 0; h < NHEAD; ++h) swst[wave][h] = sw[h];
  }
  __syncthreads();
  if (t < NHEAD) sumw_s[t] = swst[0][t] + swst[1][t] + swst[2][t] + swst[3][t];

  const int o = blockIdx.x * 32 + (t & 31);
  const int g = t >> 5;
  float a = 0.f;
  for (int b = g; b < nvblk; b += 8) a += partial_z[(size_t)b * (NHEAD * E_DIM) + o];
  red[t] = a;
  __syncthreads();
  if (t < 32) {
    float s2 = 0.f;
#pragma unroll
    for (int gg = 0; gg < 8; ++gg) s2 += red[gg * 32 + t];
    const int oo = blockIdx.x * 32 + t;
    zn[oo] = s2 / sumw_s[oo >> 10];   // oo = h*1024 + e
  }
}

// ---------------- attn[o] = Wv[o] . zn[h(o)] + bv[o] ----------------
__global__ __launch_bounds__(256) void proj_v(
    const float* __restrict__ W, const float* __restrict__ bias,
    const float* __restrict__ zn, float* __restrict__ attn)
{
  const int t = threadIdx.x, wave = t >> 6, lane = t & 63;
  const int o = blockIdx.x * 4 + wave;
  const float4* Wr = (const float4*)(W + ((size_t)2 * E_DIM + o) * E_DIM);
  const float4* zr = (const float4*)(zn + (size_t)(o >> 7) * E_DIM);
  float a = 0.f;
#pragma unroll
  for (int k = 0; k < 4; ++k) {
    float4 wv = Wr[lane + 64 * k];
    float4 zv = zr[lane + 64 * k];
    a += wv.x * zv.x + wv.y * zv.y + wv.z * zv.z + wv.w * zv.w;
  }
#pragma unroll
  for (int m = 1; m < 64; m <<= 1) a += __shfl_xor(a, m, 64);
  if (lane == 0) attn[o] = a + bias[2 * E_DIM + o];
}

// ---------------- out[e] = Wo[e] . attn + bo[e] ----------------
__global__ __launch_bounds__(256) void proj_o(
    const float* __restrict__ Wo, const float* __restrict__ bo,
    const float* __restrict__ attn, float* __restrict__ out)
{
  const int t = threadIdx.x, wave = t >> 6, lane = t & 63;
  const int o = blockIdx.x * 4 + wave;
  const float4* Wr = (const float4*)(Wo + (size_t)o * E_DIM);
  const float4* vr = (const float4*)attn;
  float a = 0.f;
#pragma unroll
  for (int k = 0; k < 4; ++k) {
    float4 wv = Wr[lane + 64 * k];
    float4 vv = vr[lane + 64 * k];
    a += wv.x * vv.x + wv.y * vv.y + wv.z * vv.z + wv.w * vv.w;
  }
#pragma unroll
  for (int m = 1; m < 64; m <<= 1) a += __shfl_xor(a, m, 64);
  if (lane == 0) out[o] = a + bo[o];
}

extern "C" void kernel_launch(void* const* d_in, const int* in_sizes, int n_in,
                              void* d_out, int out_size, void* d_ws, size_t ws_size,
                              hipStream_t stream)
{
  const float* x  = (const float*)d_in[0];   // [32768,1024]
  const float* Wi = (const float*)d_in[1];   // [3072,1024]
  const float* bi = (const float*)d_in[2];   // [3072]
  const float* Wo = (const float*)d_in[3];   // [1024,1024]
  const float* bo = (const float*)d_in[4];   // [1024]
  float* out = (float*)d_out;                // [1024] fp32

  // workspace layout (bytes)
  char* ws = (char*)d_ws;
  float* q     = (float*)(ws + 0);          // 1024 f
  float* P_T   = (float*)(ws + 4096);       // 8192 f
  float* zn    = (float*)(ws + 36864);      // 8192 f
  float* attn  = (float*)(ws + 69632);      // 1024 f
  float* psumw = (float*)(ws + 73728);      // 2*nblk*8 f (<= 32 KB)
  const size_t pz_off = 131072;
  float* pz    = (float*)(ws + pz_off);     // 2*nblk*8192 f

  // pick partial-block count from available workspace (constant across calls)
  int nblk = 128;
  if (ws_size >= pz_off + (size_t)2 * 512 * NHEAD * E_DIM * 4) nblk = 512;
  else if (ws_size >= pz_off + (size_t)2 * 256 * NHEAD * E_DIM * 4) nblk = 256;
  const int rows_per_blk = L_SEQ / nblk;
  const int nvblk = 2 * nblk;

  proj_q   <<<256, 256, 0, stream>>>(Wi, bi, x, q);
  make_p   <<<dim3(8, 8), 128, 0, stream>>>(Wi, q, P_T);
  attn_wave<<<nblk, 512, 0, stream>>>(x, P_T, pz, psumw, rows_per_blk);
  reduce_z <<<256, 256, 0, stream>>>(pz, psumw, zn, nvblk);
  proj_v   <<<256, 256, 0, stream>>>(Wi, bi, zn, attn);
  proj_o   <<<256, 256, 0, stream>>>(Wo, bo, attn, out);
}